// Round 4
// baseline (110.481 us; speedup 1.0000x reference)
//
#include <hip/hip_runtime.h>

// Problem constants
#define B_    4
#define A_    66000
#define NA_   (B_ * A_)          // 264000 anchors
#define N_    30
#define T_    5
#define NLT   5
#define CSUM  277
#define CTOT  278                // 1 + 277 logits per anchor
#define ROWS  31                 // N+1 table rows per batch
#define NROWS (B_ * ROWS)        // 124
#define WPR   16                 // u32 words per bit-row (9 used, padded)
#define NBW   (NROWS * WPR)      // 1984 words = 7936 B
#define NE    (NA_ * CTOT)       // 73,392,000 elements
#define NQ    (NE / 4)           // 18,348,000 float4s (exact)

#define BLK       256
#define GRID_CLS  2048
#define GRID_REG  512
#define CHUNK     (GRID_CLS * BLK * 4u)        // float4s consumed per outer iter = 2,097,152
#define FULLIT    (NQ / CHUNK)                 // 8 full iterations

typedef float fx4 __attribute__((ext_vector_type(4)));   // native vector: OK for nontemporal builtin

// ---------------- helpers ----------------

// focal elem, y as bit, c25/c75 = mask*0.25 / mask*0.75:
//   s = y ? -x : x;  elem = coef * softplus(s) * sigmoid(s)^2
__device__ __forceinline__ float focal_q(float x, unsigned w, unsigned sh,
                                         float c25, float c75, float acc) {
    bool y    = (w >> sh) & 1u;
    float s   = y ? -x : x;
    float coef= y ? c25 : c75;
    float t   = __expf(-fabsf(s));                 // exp(-|s|)
    float sp  = fmaxf(s, 0.f) + __logf(1.f + t);   // softplus(s)
    float inv = __builtin_amdgcn_rcpf(1.f + t);
    float sig = (s >= 0.f) ? inv : t * inv;        // sigmoid(s)
    return fmaf(coef * sp, sig * sig, acc);
}

__device__ __forceinline__ float sl1(float d) {
    float ad = fabsf(d);
    return (ad < (1.f / 9.f)) ? 4.5f * ad * ad : ad - (1.f / 18.f);
}

__device__ __forceinline__ float block_reduce(float v, float* sdata) {
    #pragma unroll
    for (int off = 32; off > 0; off >>= 1) v += __shfl_down(v, off, 64);
    int lane = threadIdx.x & 63, wid = threadIdx.x >> 6;
    if (lane == 0) sdata[wid] = v;
    __syncthreads();
    int nw = blockDim.x >> 6;
    if (wid == 0) {
        v = (lane < nw) ? sdata[lane] : 0.f;
        #pragma unroll
        for (int off = 32; off > 0; off >>= 1) v += __shfl_down(v, off, 64);
    }
    return v;
}

// process one float4 quad of conf given its (a, c0, rid); adds 4 focal terms.
__device__ __forceinline__ float do_quad(fx4 xv, unsigned a, unsigned c0, int rid,
                                         const int* __restrict__ rowid,
                                         const unsigned* lbits, float acc) {
    if (c0 != 276u) {
        unsigned bw = (rid >= 0) ? (unsigned)rid : 0u;
        unsigned w0 = lbits[bw + (c0 >> 5)];
        unsigned w1 = lbits[bw + ((c0 + 3u) >> 5)];
        unsigned sh = c0 & 31u;
        float m = (rid >= 0) ? 1.f : 0.f;
        float c25 = 0.25f * m, c75 = 0.75f * m;
        acc = focal_q(xv.x, w0, sh, c25, c75, acc);
        acc = focal_q(xv.y, w0, sh + 1u, c25, c75, acc);
        acc = focal_q(xv.z, (sh + 2u > 31u) ? w1 : w0, (sh + 2u) & 31u, c25, c75, acc);
        acc = focal_q(xv.w, (sh + 3u > 31u) ? w1 : w0, (sh + 3u) & 31u, c25, c75, acc);
    } else {  // elems 276,277 of anchor a; 0,1 of anchor a+1
        int rid2 = rowid[a + 1u];
        unsigned wA = lbits[((rid  >= 0) ? (unsigned)rid  : 0u) + 8u];
        unsigned wB = lbits[ (rid2 >= 0) ? (unsigned)rid2 : 0u];
        float mA = (rid >= 0) ? 1.f : 0.f, mB = (rid2 >= 0) ? 1.f : 0.f;
        acc = focal_q(xv.x, wA, 20u, 0.25f * mA, 0.75f * mA, acc);
        acc = focal_q(xv.y, wA, 21u, 0.25f * mA, 0.75f * mA, acc);
        acc = focal_q(xv.z, wB, 0u, 0.25f * mB, 0.75f * mB, acc);
        acc = focal_q(xv.w, wB, 1u, 0.25f * mB, 0.75f * mB, acc);
    }
    return acc;
}

// ---------------- kernels ----------------

// Bit-packed label table: 124 rows x 16 u32. Bit c of row (b*31+dumy) is the
// label y for logit column c (col 0 = pos bit, cols 1..277 = class table).
__global__ void build_bits(const int* __restrict__ gtl, unsigned* __restrict__ bits) {
    for (int i = threadIdx.x; i < NBW; i += blockDim.x) bits[i] = 0u;
    __syncthreads();
    int tid = threadIdx.x;
    if (tid < NROWS) {
        if ((tid % ROWS) > 0) atomicOr(&bits[tid * WPR], 1u);   // pos bit
    }
    if (tid < B_ * N_ * NLT) {
        int lt = tid % NLT;
        int bn = tid / NLT;
        int n  = bn % N_;
        int b  = bn / N_;
        const int nc_arr[NLT]  = {10, 23, 69, 163, 12};
        const int off_arr[NLT] = {0, 10, 33, 102, 265};
        int nc  = nc_arr[lt];
        int off = off_arr[lt] + 1;              // +1: col 0 is pos
        const int* g = gtl + (size_t)(((b * N_ + n) * NLT + lt)) * T_;
        int row = b * ROWS + (n + 1);
        bool valid = true;
        #pragma unroll
        for (int t = 0; t < T_; ++t) {
            int v = g[t];
            valid = valid && (v >= 0);
            if (valid) {
                int c = off + ((v < nc) ? v : (nc - 1));
                atomicOr(&bits[row * WPR + (c >> 5)], 1u << (c & 31));
            }
        }
    }
}

// Regression loss + pos count + per-anchor rowid (word offset into bits,
// -1 = masked-out anchor).
__global__ __launch_bounds__(BLK) void reg_rowid_kernel(
    const float* __restrict__ pred, const float* __restrict__ gt,
    const int* __restrict__ lbin, int* __restrict__ rowid,
    float* __restrict__ reg_part, float* __restrict__ pos_part)
{
    float racc = 0.f, pacc = 0.f;
    unsigned stride = gridDim.x * blockDim.x;
    for (unsigned i = blockIdx.x * blockDim.x + threadIdx.x; i < NA_; i += stride) {
        int lb = lbin[i];
        unsigned b = i / A_;
        rowid[i] = (lb < 0) ? -1 : (int)((b * ROWS + (unsigned)(lb > 0 ? lb : 0)) * WPR);
        if (lb > 0) {
            pacc += 1.f;
            float4 pv = *(const float4*)(pred + (size_t)4 * i);
            float4 gv = *(const float4*)(gt + (size_t)4 * i);
            racc += sl1(pv.x - gv.x) + sl1(pv.y - gv.y) + sl1(pv.z - gv.z) + sl1(pv.w - gv.w);
        }
    }
    __shared__ float sdata[BLK / 64];
    float r = block_reduce(racc, sdata);
    __syncthreads();
    float p = block_reduce(pacc, sdata);
    if (threadIdx.x == 0) {
        reg_part[blockIdx.x] = r;
        pos_part[blockIdx.x] = p;
    }
}

// Main classification focal-loss sum, 4x unrolled independent float4 streams.
__global__ __launch_bounds__(BLK, 4) void cls_kernel(
    const fx4* __restrict__ conf4, const int* __restrict__ rowid,
    const unsigned* __restrict__ bits, float* __restrict__ partials)
{
    __shared__ unsigned lbits[NBW];
    for (int i = threadIdx.x; i < NBW; i += BLK) lbits[i] = bits[i];
    __syncthreads();

    float acc = 0.f;
    unsigned base = blockIdx.x * (BLK * 4u) + threadIdx.x;

    for (unsigned it = 0; it < FULLIT; ++it, base += CHUNK) {
        // 1) issue 4 independent streaming loads back-to-back
        fx4 xv0 = __builtin_nontemporal_load(&conf4[base]);
        fx4 xv1 = __builtin_nontemporal_load(&conf4[base + BLK]);
        fx4 xv2 = __builtin_nontemporal_load(&conf4[base + 2u * BLK]);
        fx4 xv3 = __builtin_nontemporal_load(&conf4[base + 3u * BLK]);
        // 2) independent address math, then 4 rowid loads
        unsigned i40 = base * 4u, i41 = (base + BLK) * 4u,
                 i42 = (base + 2u * BLK) * 4u, i43 = (base + 3u * BLK) * 4u;
        unsigned a0 = i40 / CTOT, a1 = i41 / CTOT, a2 = i42 / CTOT, a3 = i43 / CTOT;
        unsigned c00 = i40 - a0 * CTOT, c01 = i41 - a1 * CTOT,
                 c02 = i42 - a2 * CTOT, c03 = i43 - a3 * CTOT;
        int r0 = rowid[a0], r1 = rowid[a1], r2 = rowid[a2], r3 = rowid[a3];
        // 3) process the 4 quads
        acc = do_quad(xv0, a0, c00, r0, rowid, lbits, acc);
        acc = do_quad(xv1, a1, c01, r1, rowid, lbits, acc);
        acc = do_quad(xv2, a2, c02, r2, rowid, lbits, acc);
        acc = do_quad(xv3, a3, c03, r3, rowid, lbits, acc);
    }

    // tail: guard each of the 4 sub-streams
    #pragma unroll
    for (unsigned k = 0; k < 4; ++k) {
        unsigned i = base + k * BLK;
        if (i < NQ) {
            fx4 xv = __builtin_nontemporal_load(&conf4[i]);
            unsigned i4 = i * 4u;
            unsigned a = i4 / CTOT;
            unsigned c0 = i4 - a * CTOT;
            acc = do_quad(xv, a, c0, rowid[a], rowid, lbits, acc);
        }
    }

    __shared__ float sdata[BLK / 64];
    float r = block_reduce(acc, sdata);
    if (threadIdx.x == 0) partials[blockIdx.x] = r;
}

// Deterministic final reduction + normalization.
__global__ void finalize_kernel(
    const float* __restrict__ cls_part, const float* __restrict__ reg_part,
    const float* __restrict__ pos_part, float* __restrict__ out)
{
    __shared__ float sdata[256 / 64];
    float c = 0.f, r = 0.f, pz = 0.f;
    for (int i = threadIdx.x; i < GRID_CLS; i += blockDim.x) c += cls_part[i];
    for (int i = threadIdx.x; i < GRID_REG; i += blockDim.x) {
        r  += reg_part[i];
        pz += pos_part[i];
    }
    c = block_reduce(c, sdata);
    __syncthreads();
    r = block_reduce(r, sdata);
    __syncthreads();
    pz = block_reduce(pz, sdata);
    if (threadIdx.x == 0) {
        float np = fmaxf(1.f, pz);
        out[0] = r / (np * 4.f);   // regression_loss
        out[1] = c / np;           // cls_loss
    }
}

// ---------------- launch ----------------

extern "C" void kernel_launch(void* const* d_in, const int* in_sizes, int n_in,
                              void* d_out, int out_size, void* d_ws, size_t ws_size,
                              hipStream_t stream) {
    const float* conf = (const float*)d_in[0];
    const float* pred = (const float*)d_in[1];
    const float* gt   = (const float*)d_in[2];
    const int*   gtl  = (const int*)d_in[3];
    const int*   lbin = (const int*)d_in[4];
    float* out = (float*)d_out;

    unsigned* bits  = (unsigned*)d_ws;
    int* rowid      = (int*)(bits + NBW);
    float* cls_part = (float*)(rowid + NA_);
    float* reg_part = cls_part + GRID_CLS;
    float* pos_part = reg_part + GRID_REG;

    hipLaunchKernelGGL(build_bits, dim3(1), dim3(1024), 0, stream, gtl, bits);
    hipLaunchKernelGGL(reg_rowid_kernel, dim3(GRID_REG), dim3(BLK), 0, stream,
                       pred, gt, lbin, rowid, reg_part, pos_part);
    hipLaunchKernelGGL(cls_kernel, dim3(GRID_CLS), dim3(BLK), 0, stream,
                       (const fx4*)conf, rowid, bits, cls_part);
    hipLaunchKernelGGL(finalize_kernel, dim3(1), dim3(256), 0, stream,
                       cls_part, reg_part, pos_part, out);
}